// Round 5
// baseline (182.893 us; speedup 1.0000x reference)
//
#include <hip/hip_runtime.h>
#include <math.h>

// Problem constants (from reference): N=100000, S=64, Q=50, P=3
#define N_Q 50
#define N_P 3
#define N_S 64
#define ROW 150        // Q*P floats per pauli word
#define BLK_ROWS 128   // rows per block (2 per lane)
#define THREADS 512    // 8 waves; wave w handles s in [8w, 8w+8)
#define WAVES 8
#define SCHUNK 8
// LDS A-tile row stride in floats: >=150, coprime with 32 (151 % 32 = 23)
// -> per-lane reads at lane*151 hit each bank exactly twice (2-way = free).
#define ASTRIDE 151

// ws layout (bytes):
//   [0      .. 6256)    partials double[782]
//   [6272   .. +4)      done-counter int (zeroed by precompute each launch)
//   [6336   .. +38400)  HP   float[Q][S][3]  normalized heads, q-major
//   [44736  .. +256)    hrv  float[S]        smoothed head ratios
#define WS_CNT_OFF 6272
#define WS_HP_OFF 6336
#define WS_HRV_OFF 44736

__device__ __forceinline__ float softplus20(float x) {
    float z = x * 20.0f;
    return fmaxf(z, 0.0f) + log1pf(expf(-fabsf(z)));  // stable softplus
}

__global__ void precompute_kernel(const float* __restrict__ heads_param,
                                  const float* __restrict__ hr_param,
                                  float* __restrict__ HP,
                                  float* __restrict__ hrv,
                                  int* __restrict__ cnt) {
    const int tid = threadIdx.x;
    if (blockIdx.x == 0) {
        if (tid == 0) *cnt = 0;  // ws is re-poisoned every launch
        if (tid < N_S) {
            float sp = softplus20(hr_param[tid]);
            float tot = sp;
            #pragma unroll
            for (int off = 32; off; off >>= 1) tot += __shfl_xor(tot, off);
            float hr = sp / fmaxf(tot, 1e-12f);
            hrv[tid] = (hr + 0.001f / (float)N_S) / 1.001f;
        }
    }
    // EXACT reference semantics: h_p = sp_p / max(sum, EPS); when the clamp
    // fires the row does NOT sum to 1, so all three components are stored.
    int idx = blockIdx.x * blockDim.x + tid;
    if (idx < N_S * N_Q) {
        int q = idx / N_S;
        int s = idx - q * N_S;
        const float* hp = heads_param + ((size_t)s * N_Q + q) * N_P;
        float sp0 = softplus20(hp[0]);
        float sp1 = softplus20(hp[1]);
        float sp2 = softplus20(hp[2]);
        float denom = fmaxf(sp0 + sp1 + sp2, 1e-12f);
        float* o = HP + ((size_t)q * N_S + s) * 3;
        o[0] = sp0 / denom;
        o[1] = sp1 / denom;
        o[2] = sp2 / denom;
    }
}

// One q, 8 s-values (2 groups of 4), applied to TWO rows sharing the H reads.
// Hq points at GLOBAL HP with a wave-uniform address -> the coalescer merges
// each float4 load into a single L1/L2 line request (H is cache-resident).
// Math order identical to the verified round-0/round-4 kernels.
__device__ __forceinline__ void computeQ2(const float4* __restrict__ Hq,
                                          float a0, float a1, float a2,
                                          float c0, float c1, float c2,
                                          float (&p)[SCHUNK], float (&p2)[SCHUNK]) {
    #pragma unroll
    for (int g = 0; g < SCHUNK / 4; ++g) {
        float4 b0 = Hq[3 * g], b1 = Hq[3 * g + 1], b2 = Hq[3 * g + 2];
        // layout per 4 s: [h00 h01 h02 h10][h11 h12 h20 h21][h22 h30 h31 h32]
        p [4*g+0] *= fmaf(b0.x, a0, fmaf(b0.y, a1, b0.z * a2));
        p2[4*g+0] *= fmaf(b0.x, c0, fmaf(b0.y, c1, b0.z * c2));
        p [4*g+1] *= fmaf(b0.w, a0, fmaf(b1.x, a1, b1.y * a2));
        p2[4*g+1] *= fmaf(b0.w, c0, fmaf(b1.x, c1, b1.y * c2));
        p [4*g+2] *= fmaf(b1.z, a0, fmaf(b1.w, a1, b2.x * a2));
        p2[4*g+2] *= fmaf(b1.z, c0, fmaf(b1.w, c1, b2.x * c2));
        p [4*g+3] *= fmaf(b2.y, a0, fmaf(b2.z, a1, b2.w * a2));
        p2[4*g+3] *= fmaf(b2.y, c0, fmaf(b2.z, c1, b2.w * c2));
    }
}

__global__ __launch_bounds__(THREADS, 4) void main_kernel(
    const float* __restrict__ A, const float* __restrict__ coeff,
    const float* __restrict__ HP, const float* __restrict__ hrv,
    double* __restrict__ partials, int* __restrict__ cnt,
    float* __restrict__ out, int N) {
    // A-tile: 128 rows x 151-float stride = 77312 B. After the main loop the
    // tile is dead; its front is reused (behind a barrier) as covs[8][128].
    __shared__ float Atile[BLK_ROWS * ASTRIDE];
    __shared__ double redd[2];
    __shared__ double redf[WAVES];
    __shared__ int isLast;

    const int tid = threadIdx.x;
    const int lane = tid & 63;
    const int wave = tid >> 6;
    const int nbase = blockIdx.x * BLK_ROWS;

    // --- stage A rows into LDS: coalesced float2 global reads (9600 x 8B) ---
    {
        const float2* __restrict__ Asrc = (const float2*)A;
        for (int g = tid; g < BLK_ROWS * (ROW / 2); g += THREADS) {
            int r = g / (ROW / 2);
            int j = g - r * (ROW / 2);
            int src = nbase + r; if (src >= N) src = N - 1;
            float2 v = Asrc[(size_t)src * (ROW / 2) + j];
            Atile[r * ASTRIDE + 2 * j]     = v.x;
            Atile[r * ASTRIDE + 2 * j + 1] = v.y;
        }
    }
    __syncthreads();

    // lane owns rows lane and lane+64 of the tile (same rows for all 8 waves)
    const float* __restrict__ Ar0 = Atile + lane * ASTRIDE;
    const float* __restrict__ Ar1 = Atile + (lane + 64) * ASTRIDE;

    float prod0[SCHUNK], prod1[SCHUNK];
    #pragma unroll
    for (int i = 0; i < SCHUNK; ++i) { prod0[i] = 1.0f; prod1[i] = 1.0f; }

    // H base for this wave's s-chunk in GLOBAL HP: q-row = 48 float4
    const float4* __restrict__ Hbase = (const float4*)HP + 6 * wave;

    #pragma unroll 5
    for (int w = 0; w < N_Q / 2; ++w) {   // window = 2 q = 6 floats/row
        const int o = 6 * w;
        float a0 = Ar0[o], a1 = Ar0[o+1], a2 = Ar0[o+2];
        float a3 = Ar0[o+3], a4 = Ar0[o+4], a5 = Ar0[o+5];
        float c0 = Ar1[o], c1 = Ar1[o+1], c2 = Ar1[o+2];
        float c3 = Ar1[o+3], c4 = Ar1[o+4], c5 = Ar1[o+5];
        const float4* Hq = Hbase + 96 * w;      // q = 2w
        computeQ2(Hq,      a0, a1, a2,  c0, c1, c2, prod0, prod1);
        computeQ2(Hq + 48, a3, a4, a5,  c3, c4, c5, prod0, prod1);
    }

    // ratio-weighted partials for both rows (hrv: tiny, wave-uniform, cached)
    float acc0 = 0.0f, acc1 = 0.0f;
    const float* __restrict__ hw = hrv + wave * SCHUNK;
    #pragma unroll
    for (int i = 0; i < SCHUNK; ++i) {
        float wgt = hw[i];
        acc0 = fmaf(wgt, prod0[i], acc0);
        acc1 = fmaf(wgt, prod1[i], acc1);
    }

    __syncthreads();                     // all A-tile reads complete
    float* __restrict__ covs = Atile;    // alias: covs[wave][row], 4096 B
    covs[wave * BLK_ROWS + lane]      = acc0;
    covs[wave * BLK_ROWS + 64 + lane] = acc1;
    __syncthreads();

    // waves 0,1 finalize rows 0..63 / 64..127 (sequential 8-wave cov sum,
    // same association as the verified round-4 finalize: absmax stayed 0)
    if (wave < 2) {
        const int row = wave * 64 + lane;
        const int n = nbase + row;
        float cov = 0.0f;
        #pragma unroll
        for (int wv = 0; wv < WAVES; ++wv) cov += covs[wv * BLK_ROWS + row];
        float term = 0.0f;
        if (n < N) { float c = coeff[n]; term = (c * c) / cov; }
        double td = (double)term;
        #pragma unroll
        for (int off = 32; off; off >>= 1) td += __shfl_down(td, off);
        if (lane == 0) redd[wave] = td;
    }
    __syncthreads();

    if (tid == 0) {
        partials[blockIdx.x] = redd[0] + redd[1];
        __threadfence();                 // release partial
        int v = atomicAdd(cnt, 1);
        isLast = (v == (int)gridDim.x - 1);
    }
    __syncthreads();

    if (isLast) {                        // last-finishing block reduces all
        __threadfence();                 // acquire
        double s = 0.0;
        for (int i = tid; i < (int)gridDim.x; i += THREADS) s += partials[i];
        #pragma unroll
        for (int off = 32; off; off >>= 1) s += __shfl_down(s, off);
        if (lane == 0) redf[wave] = s;
        __syncthreads();
        if (tid == 0) {
            double t = 0.0;
            #pragma unroll
            for (int wv = 0; wv < WAVES; ++wv) t += redf[wv];
            out[0] = (float)t;
        }
    }
}

extern "C" void kernel_launch(void* const* d_in, const int* in_sizes, int n_in,
                              void* d_out, int out_size, void* d_ws, size_t ws_size,
                              hipStream_t stream) {
    const float* A           = (const float*)d_in[0];  // [N, Q, P]
    const float* coeff       = (const float*)d_in[1];  // [N]
    const float* heads_param = (const float*)d_in[2];  // [S, Q, P]
    const float* hr_param    = (const float*)d_in[3];  // [S]
    const int N = in_sizes[1];
    const int nblocks = (N + BLK_ROWS - 1) / BLK_ROWS;  // 782

    char* ws = (char*)d_ws;
    double* partials = (double*)ws;
    int*   cnt = (int*)(ws + WS_CNT_OFF);
    float* HP  = (float*)(ws + WS_HP_OFF);
    float* hrv = (float*)(ws + WS_HRV_OFF);
    float* out = (float*)d_out;

    const int pre_blocks = (N_S * N_Q + THREADS - 1) / THREADS;  // 7
    precompute_kernel<<<pre_blocks, THREADS, 0, stream>>>(heads_param, hr_param,
                                                          HP, hrv, cnt);
    main_kernel<<<nblocks, THREADS, 0, stream>>>(A, coeff, HP, hrv, partials,
                                                 cnt, out, N);
}